// Round 12
// baseline (366.677 us; speedup 1.0000x reference)
//
#include <hip/hip_runtime.h>
#include <type_traits>

#define N 4096

// ======== iterative (border) kernel params — round-11 proven ========
#define TILE 96
#define HALO 16
#define SDIM 128
#define NSTRIP 16
#define GH 8
#define NSTEPS 16
#define NB 43
#define SPAD 132

// ======== separable diagonal-conv params ========
#define PX 64      // output tile width
#define PY 32      // output tile height
#define SROWS 64   // staged rows = PY + 32
#define SCOLS 96   // staged cols = PX + 32
#define SSTR 100   // LDS row stride in words (100 % 32 = 4 -> row bank de-phase)

// C(32,k) — binomial weights of (S+S^-1)^32; sum = 2^32 per pass.
__device__ constexpr float BIN32[33] = {
    1.f, 32.f, 496.f, 4960.f, 35960.f, 201376.f, 906192.f, 3365856.f,
    10518300.f, 28048800.f, 64512240.f, 129024480.f, 225792840.f,
    347373600.f, 471435600.f, 565722720.f, 601080390.f, 565722720.f,
    471435600.f, 347373600.f, 225792840.f, 129024480.f, 64512240.f,
    28048800.f, 10518300.f, 3365856.f, 906192.f, 201376.f, 35960.f,
    4960.f, 496.f, 32.f, 1.f};

// DPP lane shifts within 16-lane rows. row_shr:1 -> dest[i]=src[i-1];
// row_shl:1 -> dest[i]=src[i+1]. Boundary lanes keep own value (feeds only the
// never-consumed staging-edge cols).
__device__ __forceinline__ float dpp_prev(float x) {
    int r = __builtin_amdgcn_update_dpp(__float_as_int(x), __float_as_int(x),
                                        0x111, 0xf, 0xf, false);
    return __int_as_float(r);
}
__device__ __forceinline__ float dpp_next(float x) {
    int r = __builtin_amdgcn_update_dpp(__float_as_int(x), __float_as_int(x),
                                        0x101, 0xf, 0xf, false);
    return __int_as_float(r);
}

// Diffuse/AO shading for 4 pixels (rx carries 2^64 deferred scale).
__device__ __forceinline__ float4 shade(float4 v, float4 h, float4 n0, float4 n1, float4 n2) {
    const float SC = 0x1p-64f;
    const float L0 = 0.7053f, L1 = -0.7053f, L2 = 0.7053f;
    float4 o;
    {
        float ao = 1.0f - fminf(fmaxf((v.x * SC - h.x) * 4.0f, 0.0f), 1.0f);
        float d1 = fmaxf(n0.x * L0 + n1.x * L1 + n2.x * L2, 0.0f);
        o.x = (d1 * 0.3f + 0.7f) * ao;
    }
    {
        float ao = 1.0f - fminf(fmaxf((v.y * SC - h.y) * 4.0f, 0.0f), 1.0f);
        float d1 = fmaxf(n0.y * L0 + n1.y * L1 + n2.y * L2, 0.0f);
        o.y = (d1 * 0.3f + 0.7f) * ao;
    }
    {
        float ao = 1.0f - fminf(fmaxf((v.z * SC - h.z) * 4.0f, 0.0f), 1.0f);
        float d1 = fmaxf(n0.z * L0 + n1.z * L1 + n2.z * L2, 0.0f);
        o.z = (d1 * 0.3f + 0.7f) * ao;
    }
    {
        float ao = 1.0f - fminf(fmaxf((v.w * SC - h.w) * 4.0f, 0.0f), 1.0f);
        float d1 = fmaxf(n0.w * L0 + n1.w * L1 + n2.w * L2, 0.0f);
        o.w = (d1 * 0.3f + 0.7f) * ao;
    }
    return o;
}

// ---------------- iterative 16-step kernel (round 11), band-restricted ----------------
// BAND: 1 = ring (border tiles + 1 neighbor ring, pass 1), 2 = border tiles only (pass 2).
template <int FUSE, int BAND>
__global__ __launch_bounds__(256, 2) void stencil16(const float* __restrict__ src,
                                                    float* __restrict__ dst,
                                                    const float* __restrict__ xin,
                                                    const float* __restrict__ nrm) {
    const int bx = blockIdx.x, by = blockIdx.y;
    if constexpr (BAND == 1) {
        if (!(bx <= 1 || bx >= NB - 2 || by <= 1 || by >= NB - 2)) return;
    } else {
        if (!(bx == 0 || bx == NB - 1 || by == 0 || by == NB - 1)) return;
    }
    __shared__ float bnd[2][2][NSTRIP][SPAD];
    const int gi0 = by * TILE - HALO;
    const int gj0 = bx * TILE - HALO;
    const int tid = (int)threadIdx.x;
    const int g   = tid >> 4;
    const int l   = tid & 15;
    const int jc  = 8 * l;
    const int r0  = 8 * g;
    const bool edge = (bx == 0) | (by == 0) | (bx == NB - 1) | (by == NB - 1);

    float4 ra[GH], rb[GH];

    if (!edge) {
        const float* base = src + (size_t)(gi0 + r0) * N + (gj0 + jc);
#pragma unroll
        for (int k = 0; k < GH; ++k) {
            ra[k] = *(const float4*)(base + (size_t)k * N);
            rb[k] = *(const float4*)(base + (size_t)k * N + 4);
        }
    } else {
        auto ld4 = [&](int r, int c0) -> float4 {
            int gr = gi0 + r;
            gr = gr < 0 ? 0 : (gr > N - 1 ? N - 1 : gr);
            const int gc = gj0 + c0;
            if (gc >= 0 && gc + 3 <= N - 1)
                return *(const float4*)(src + (size_t)gr * N + gc);
            const float* row = src + (size_t)gr * N;
            return make_float4(row[min(max(gc + 0, 0), N - 1)],
                               row[min(max(gc + 1, 0), N - 1)],
                               row[min(max(gc + 2, 0), N - 1)],
                               row[min(max(gc + 3, 0), N - 1)]);
        };
#pragma unroll
        for (int k = 0; k < GH; ++k) {
            ra[k] = ld4(r0 + k, jc);
            rb[k] = ld4(r0 + k, jc + 4);
        }
    }

    const int gc0 = gj0 + jc;
    const bool lcl = edge && (gc0 == 0);
    const bool rcl = edge && (gc0 + 7 == N - 1);

    *(float4*)&bnd[0][0][g][jc]     = ra[0];
    *(float4*)&bnd[0][0][g][jc + 4] = rb[0];
    *(float4*)&bnd[0][1][g][jc]     = ra[GH - 1];
    *(float4*)&bnd[0][1][g][jc + 4] = rb[GH - 1];
    __syncthreads();

    const int gm = (g == 0) ? 0 : g - 1;
    const int gp = (g == NSTRIP - 1) ? NSTRIP - 1 : g + 1;

    auto run = [&](auto EC) {
#pragma unroll 1
        for (int p = 0; p < NSTEPS; ++p) {
            const int s = p + 1;
            const int cbuf = p & 1;
            float4 ua = *(const float4*)&bnd[cbuf][1][gm][jc];
            float4 ub = *(const float4*)&bnd[cbuf][1][gm][jc + 4];
            float4 da = *(const float4*)&bnd[cbuf][0][gp][jc];
            float4 db = *(const float4*)&bnd[cbuf][0][gp][jc + 4];
            float4 pa = ua, pb = ub;
#pragma unroll
            for (int k = 0; k < GH; ++k) {
                const int r = r0 + k;
                const float4 ca = ra[k], cb = rb[k];
                const float4 na  = (k < GH - 1) ? ra[k + 1] : da;
                const float4 nb2 = (k < GH - 1) ? rb[k + 1] : db;
                if (r >= s && r < SDIM - s) {
                    float lft = dpp_prev(cb.w);
                    float rgt = dpp_next(ca.x);
                    float4 upa = pa, upb = pb, dna = na, dnb = nb2;
                    if constexpr (decltype(EC)::value) {
                        const int gr = gi0 + r;
                        if (gr == 0)     { upa = ca; upb = cb; }
                        if (gr == N - 1) { dna = ca; dnb = cb; }
                        if (lcl) lft = ca.x;
                        if (rcl) rgt = cb.w;
                    }
                    float4 oa, ob;
                    oa.x = (upa.x + dna.x) + (lft  + ca.y);
                    oa.y = (upa.y + dna.y) + (ca.x + ca.z);
                    oa.z = (upa.z + dna.z) + (ca.y + ca.w);
                    oa.w = (upa.w + dna.w) + (ca.z + cb.x);
                    ob.x = (upb.x + dnb.x) + (ca.w + cb.y);
                    ob.y = (upb.y + dnb.y) + (cb.x + cb.z);
                    ob.z = (upb.z + dnb.z) + (cb.y + cb.w);
                    ob.w = (upb.w + dnb.w) + (cb.z + rgt);
                    ra[k] = oa; rb[k] = ob;
                }
                pa = ca; pb = cb;
            }
            const int nbuf = cbuf ^ 1;
            *(float4*)&bnd[nbuf][0][g][jc]     = ra[0];
            *(float4*)&bnd[nbuf][0][g][jc + 4] = rb[0];
            *(float4*)&bnd[nbuf][1][g][jc]     = ra[GH - 1];
            *(float4*)&bnd[nbuf][1][g][jc + 4] = rb[GH - 1];
            __syncthreads();
        }
    };
    if (edge) run(std::true_type{});
    else      run(std::false_type{});

    if (l >= HALO / 8 && l < (SDIM - HALO) / 8) {
#pragma unroll
        for (int k = 0; k < GH; ++k) {
            const int r = r0 + k;
            if (r < HALO || r >= SDIM - HALO) continue;
            const int gr = gi0 + r;
            if (edge && gr >= N) continue;
            const size_t base = (size_t)gr * N + gc0;
            const bool ok_a = !edge || (gc0 + 3 <= N - 1);
            const bool ok_b = !edge || (gc0 + 7 <= N - 1);
            if constexpr (FUSE) {
                if (ok_a) {
                    const float4 h  = *(const float4*)(xin + base);
                    const float4 n0 = *(const float4*)(nrm + base);
                    const float4 n1 = *(const float4*)(nrm + (size_t)N * N + base);
                    const float4 n2 = *(const float4*)(nrm + 2 * (size_t)N * N + base);
                    *(float4*)(dst + base) = shade(ra[k], h, n0, n1, n2);
                }
                if (ok_b) {
                    const float4 h  = *(const float4*)(xin + base + 4);
                    const float4 n0 = *(const float4*)(nrm + base + 4);
                    const float4 n1 = *(const float4*)(nrm + (size_t)N * N + base + 4);
                    const float4 n2 = *(const float4*)(nrm + 2 * (size_t)N * N + base + 4);
                    *(float4*)(dst + base + 4) = shade(rb[k], h, n0, n1, n2);
                }
            } else {
                if (ok_a) *(float4*)(dst + base)     = ra[k];
                if (ok_b) *(float4*)(dst + base + 4) = rb[k];
            }
        }
    }
}

// ---------------- separable 33-tap diagonal convolution ----------------
// A^32 = (Su+Su^-1)^32 (Sv+Sv^-1)^32 in rotated coords u=x+y, v=x-y.
// DIR=0 (P1): t(x,y)   = sum_k C(32,k) f(x+k-16, y-(k-16))   [anti-diagonal]
// DIR=1 (P2): out(x,y) = sum_k C(32,k) t(x+k-16, y+(k-16))   [diagonal]
// Valid for outputs >= 32 (Linf) from borders (dependency cone = L1 ball r=32,
// never touches the pad). Thread owns 8 consecutive x; 8-aligned columns make
// the per-tap window extraction compile-time static.
template <int DIR, int FUSE>
__global__ __launch_bounds__(256) void diagconv(const float* __restrict__ src,
                                                float* __restrict__ dst,
                                                const float* __restrict__ xin,
                                                const float* __restrict__ nrm) {
    __shared__ float lds[SROWS * SSTR];   // 25.6 KB
    const int X0 = blockIdx.x * PX;
    const int Y0 = blockIdx.y * PY;
    const int tid = (int)threadIdx.x;

    // stage [Y0-16, Y0+48) x [X0-16, X0+80)
    const bool inter = (X0 >= 16) && (X0 + 80 <= N) && (Y0 >= 16) && (Y0 + 48 <= N);
    if (inter) {
        for (int idx = tid; idx < SROWS * (SCOLS / 4); idx += 256) {
            const int r = idx / (SCOLS / 4), q = idx % (SCOLS / 4);
            const float4 v = *(const float4*)(src + (size_t)(Y0 - 16 + r) * N + (X0 - 16 + 4 * q));
            *(float4*)&lds[r * SSTR + 4 * q] = v;
        }
    } else {
        for (int idx = tid; idx < SROWS * (SCOLS / 4); idx += 256) {
            const int r = idx / (SCOLS / 4), q = idx % (SCOLS / 4);
            int gy = Y0 - 16 + r; gy = gy < 0 ? 0 : (gy > N - 1 ? N - 1 : gy);
            const int gx = X0 - 16 + 4 * q;
            const float* row = src + (size_t)gy * N;
            float4 v;
            if (gx >= 0 && gx + 3 < N) v = *(const float4*)(row + gx);
            else v = make_float4(row[min(max(gx + 0, 0), N - 1)],
                                 row[min(max(gx + 1, 0), N - 1)],
                                 row[min(max(gx + 2, 0), N - 1)],
                                 row[min(max(gx + 3, 0), N - 1)]);
            *(float4*)&lds[r * SSTR + 4 * q] = v;
        }
    }
    __syncthreads();

    const int ol = 8 * (tid & 7);   // output local x 0..56
    const int yl = tid >> 3;        // output local y 0..31

    float acc[8] = {0.f, 0.f, 0.f, 0.f, 0.f, 0.f, 0.f, 0.f};
#pragma unroll
    for (int k = 0; k <= 32; ++k) {
        const int rr = DIR ? (yl + k) : (yl + 32 - k);
        const int cb = ol + (k & ~3);               // aligned window base
        const float* p = &lds[rr * SSTR + cb];
        const float4 w0 = *(const float4*)(p);
        const float4 w1 = *(const float4*)(p + 4);
        const float4 w2 = *(const float4*)(p + 8);
        const float vals[12] = {w0.x, w0.y, w0.z, w0.w, w1.x, w1.y, w1.z, w1.w,
                                w2.x, w2.y, w2.z, w2.w};
        const float c = BIN32[k];
        const int off = k & 3;                      // compile-time after unroll
#pragma unroll
        for (int i = 0; i < 8; ++i) acc[i] = fmaf(c, vals[off + i], acc[i]);
    }

    const int gx0 = X0 + ol;
    const int gy  = Y0 + yl;
    const float4 va = make_float4(acc[0], acc[1], acc[2], acc[3]);
    const float4 vb = make_float4(acc[4], acc[5], acc[6], acc[7]);
    const size_t base = (size_t)gy * N + gx0;

    if constexpr (!FUSE) {
        // P1: store everywhere (values <16 from border are garbage but feed
        // only discarded P2 outputs).
        *(float4*)(dst + base)     = va;
        *(float4*)(dst + base + 4) = vb;
    } else {
        // P2: only outputs >= 32 (Linf) from borders are separable-valid.
        if (gy >= 32 && gy < N - 32) {
            if (gx0 >= 32 && gx0 + 3 < N - 32) {
                const float4 h  = *(const float4*)(xin + base);
                const float4 n0 = *(const float4*)(nrm + base);
                const float4 n1 = *(const float4*)(nrm + (size_t)N * N + base);
                const float4 n2 = *(const float4*)(nrm + 2 * (size_t)N * N + base);
                *(float4*)(dst + base) = shade(va, h, n0, n1, n2);
            }
            if (gx0 + 4 >= 32 && gx0 + 7 < N - 32) {
                const float4 h  = *(const float4*)(xin + base + 4);
                const float4 n0 = *(const float4*)(nrm + base + 4);
                const float4 n1 = *(const float4*)(nrm + (size_t)N * N + base + 4);
                const float4 n2 = *(const float4*)(nrm + 2 * (size_t)N * N + base + 4);
                *(float4*)(dst + base + 4) = shade(vb, h, n0, n1, n2);
            }
        }
    }
}

extern "C" void kernel_launch(void* const* d_in, const int* in_sizes, int n_in,
                              void* d_out, int out_size, void* d_ws, size_t ws_size,
                              hipStream_t stream) {
    const float* x       = (const float*)d_in[0];
    const float* normals = (const float*)d_in[1];
    float* out = (float*)d_out;
    float* ws  = (float*)d_ws;

    dim3 gridI(NB, NB);
    dim3 gridP(N / PX, N / PY);
    dim3 block(256);

    // Border band (exact iterative, 2x16 steps): ring tiles -> ws, border tiles -> out.
    stencil16<0, 1><<<gridI, block, 0, stream>>>(x,  ws,  nullptr, nullptr);
    stencil16<1, 2><<<gridI, block, 0, stream>>>(ws, out, x, normals);
    // Interior (separable diagonal binomial): P1 anti-diag -> ws, P2 diag -> out.
    diagconv<0, 0><<<gridP, block, 0, stream>>>(x,  ws,  nullptr, nullptr);
    diagconv<1, 1><<<gridP, block, 0, stream>>>(ws, out, x, normals);
}